// Round 17
// baseline (48.671 us; speedup 1.0000x reference)
//
#include <hip/hip_runtime.h>

#define NATOMS 13
#define NP (NATOMS * NATOMS)   // 169

constexpr int N_ = 1024;   // rows
constexpr int H_ = 512;    // inner dim
constexpr int O_ = 512;    // output dim
constexpr int OC = 256;    // cols per o-half (1KB contiguous wave reads)
constexpr int HH = 256;    // h rows per h-half
constexpr int MAXPAIR = 600;           // >= sum ceil(c_g/2) (<=596)
constexpr int NSEL = 4;                // o-half x h-half
constexpr int NB = MAXPAIR * NSEL;     // 2400 blocks (div by 8)
constexpr int RECS = 4;    // ints per pair record: row0, row1, id, pad
constexpr int PART_OFF = 8192;         // int offset of partial buffers in ws

// ws ints: [0] npairs; records at ws+16; partials (2 x N_ x O_ floats) at +8192
// ----------------------------------------------------------------- build pairs
// R15-style latency-optimized build: 1024 threads, packed Hillis-Steele scan
// (lo16: row starts, hi16: pair starts).
__global__ __launch_bounds__(1024)
void build_pairs(const int* __restrict__ x,
                 const int* __restrict__ fact,
                 int* __restrict__ ws, int N) {
    __shared__ int s_id[N_];
    __shared__ int s_cnt[NP];
    __shared__ int s_pos[NP];
    __shared__ int s_scan[256];
    __shared__ int s_sorted[N_];
    const int tid = threadIdx.x;

    if (tid < NP) { s_cnt[tid] = 0; s_pos[tid] = 0; }
    __syncthreads();

    int id = -1;
    if (tid < N) {
        const int f0 = fact[2 * tid];
        id = x[f0 * 3 + 1] * NATOMS + x[f0 * 3 + 2];
        s_id[tid] = id;
        atomicAdd(&s_cnt[id], 1);
    }
    __syncthreads();

    if (tid < 256) {
        const int c = (tid < NP) ? s_cnt[tid] : 0;
        s_scan[tid] = c | (((c + 1) >> 1) << 16);
    }
    __syncthreads();
#pragma unroll
    for (int off = 1; off < 256; off <<= 1) {
        int nv = 0;
        if (tid < 256) {
            nv = s_scan[tid];
            if (tid >= off) nv += s_scan[tid - off];
        }
        __syncthreads();
        if (tid < 256) s_scan[tid] = nv;
        __syncthreads();
    }
    if (tid == 0) ws[0] = s_scan[NP - 1] >> 16;   // npairs

    if (tid < N) {
        const int st_me = id ? (s_scan[id - 1] & 0xffff) : 0;
        const int p = atomicAdd(&s_pos[id], 1);
        s_sorted[st_me + p] = tid;
    }
    __syncthreads();

    if (tid < NP) {
        const int g  = tid;
        const int c  = s_cnt[g];
        const int st = g ? (s_scan[g - 1] & 0xffff) : 0;
        const int ps = g ? (s_scan[g - 1] >> 16) : 0;
        const int npair = (c + 1) >> 1;
        for (int k = 0; k < npair; ++k) {
            int* rec = ws + 16 + (size_t)(ps + k) * RECS;
            rec[0] = s_sorted[st + 2 * k];
            rec[1] = (2 * k + 1 < c) ? s_sorted[st + 2 * k + 1] : -1;
            rec[2] = g;
        }
    }
}

// ------------------------------------------------------------------ pair GEMV
// One block per (pair, o-half, h-half), 128 threads = 2 waves. Each block
// streams a 256x256 W chunk (256KB) with R9's proven pattern: wave sub reads
// rows h0+2*hh+sub as 1KB-contiguous loads (4KB stride). Partials stored
// DIRECTLY (no atomics) into ws partial[hh]; bias folded in by hh==0 blocks.
__global__ __launch_bounds__(128)
void pair_gemv(int* __restrict__ ws,
               const float* __restrict__ inp,
               const float* __restrict__ params,
               const float* __restrict__ bias,
               const int* __restrict__ msg_to_p,
               const int* __restrict__ order_p,
               int N) {
    // bijective XCD-chunked swizzle (NB % 8 == 0): the 4 panels of a pair and
    // neighboring pairs (same group -> same W) share an XCD.
    constexpr int q8 = NB / 8;
    const int b = blockIdx.x;
    const int Lg = (b & 7) * q8 + (b >> 3);
    const int pair = Lg >> 2;
    const int sel  = Lg & 3;
    const int oh   = sel & 1;
    const int hhf  = sel >> 1;

    if (pair >= ws[0]) return;
    const int* rec = ws + 16 + (size_t)pair * RECS;
    const int row0 = rec[0];
    const int row1 = rec[1];
    const int id   = rec[2];

    const int msg_to = *msg_to_p;
    const int order  = *order_p;
    const int tid = threadIdx.x;
    const int sub = tid >> 6;        // 0..1: h-parity within the half
    const int l   = tid & 63;        // col-quad within 256-col panel
    const int o0  = oh * OC;
    const int h0  = hhf * HH;

    __shared__ float  fp_s[HH][2];       // 2 KB, [h][r]
    __shared__ float4 red[2][2][64];     // 4 KB, [sub][r][l]

    // stage fact_prod for h in [h0, h0+256), both rows (coalesced 512B loads)
#pragma unroll
    for (int k2 = 0; k2 < HH / 128; ++k2) {
        const int h = h0 + k2 * 128 + tid;
        float p0 = 1.0f, p1 = 0.0f;
        for (int i = 0; i < order; ++i)
            if (i != msg_to)
                p0 *= inp[((size_t)i * N + row0) * H_ + h];
        if (row1 >= 0) {
            p1 = 1.0f;
            for (int i = 0; i < order; ++i)
                if (i != msg_to)
                    p1 *= inp[((size_t)i * N + row1) * H_ + h];
        }
        fp_s[k2 * 128 + tid][0] = p0;
        fp_s[k2 * 128 + tid][1] = p1;
    }
    __syncthreads();

    // wave sub streams rows h0 + 2*hh2 + sub, hh2 in [0,128): 1KB wave loads
    const float* __restrict__ wbase =
        params + (size_t)id * H_ * O_ + (size_t)(h0 + sub) * O_ + o0 + 4 * l;

    float4 a0 = make_float4(0,0,0,0), a1 = a0;

#define FMA4(acc, s, wv) acc.x += (s) * wv.x; acc.y += (s) * wv.y;    \
                         acc.z += (s) * wv.z; acc.w += (s) * wv.w;
#pragma unroll 8
    for (int hh2 = 0; hh2 < HH / 2; ++hh2) {
        const float4 w = *(const float4*)(wbase + (size_t)hh2 * 2 * O_);
        const float2 f = *(const float2*)&fp_s[2 * hh2 + sub][0];
        FMA4(a0, f.x, w)
        FMA4(a1, f.y, w)
    }
#undef FMA4

    red[sub][0][l] = a0;
    red[sub][1][l] = a1;
    __syncthreads();

    // thread (sub, l) emits row rec[sub] into partial[hhf]
    const int row = (sub == 0) ? row0 : row1;
    if (row >= 0) {
        const float4 p0 = red[0][sub][l];
        const float4 p1 = red[1][sub][l];
        float4 s;
        s.x = p0.x + p1.x;
        s.y = p0.y + p1.y;
        s.z = p0.z + p1.z;
        s.w = p0.w + p1.w;
        if (hhf == 0) {   // bias exactly once per (row, col)
            const float4 bv = *(const float4*)(bias + (size_t)id * O_ + o0 + 4 * l);
            s.x += bv.x; s.y += bv.y; s.z += bv.z; s.w += bv.w;
        }
        float* part = (float*)(ws + PART_OFF) + (size_t)hhf * N_ * O_;
        *(float4*)(part + (size_t)row * O_ + o0 + 4 * l) = s;
    }
}

// -------------------------------------------------------------------- combine
// out = partial[0] + partial[1]. 512 blocks x 256 threads, one float4 each.
__global__ __launch_bounds__(256)
void combine(const int* __restrict__ ws, float* __restrict__ out) {
    const int idx = blockIdx.x * 256 + threadIdx.x;   // 0 .. 131071
    const float* part = (const float*)(ws + PART_OFF);
    const float4 p0 = *(const float4*)(part + (size_t)4 * idx);
    const float4 p1 = *(const float4*)(part + (size_t)N_ * O_ + (size_t)4 * idx);
    float4 s;
    s.x = p0.x + p1.x;
    s.y = p0.y + p1.y;
    s.z = p0.z + p1.z;
    s.w = p0.w + p1.w;
    *(float4*)(out + (size_t)4 * idx) = s;
}

// ---------------------------------------------------------------------- launch
extern "C" void kernel_launch(void* const* d_in, const int* in_sizes, int n_in,
                              void* d_out, int out_size, void* d_ws, size_t ws_size,
                              hipStream_t stream) {
    const int*   x      = (const int*)d_in[0];
    const int*   fact   = (const int*)d_in[1];
    const float* inp    = (const float*)d_in[2];
    const float* params = (const float*)d_in[3];
    const float* bias   = (const float*)d_in[4];
    const int*   msg_to = (const int*)d_in[5];
    const int*   order  = (const int*)d_in[6];
    float*       out    = (float*)d_out;

    const int N = in_sizes[1] / 2;   // 1024
    int* ws = (int*)d_ws;

    hipLaunchKernelGGL(build_pairs, dim3(1), dim3(1024), 0, stream,
                       x, fact, ws, N);

    hipLaunchKernelGGL(pair_gemv, dim3(NB), dim3(128), 0, stream,
                       ws, inp, params, bias, msg_to, order, N);

    hipLaunchKernelGGL(combine, dim3((N_ * O_ / 4) / 256), dim3(256), 0, stream,
                       ws, out);
}

// Round 18
// 43.949 us; speedup vs baseline: 1.1074x; 1.1074x over previous
//
#include <hip/hip_runtime.h>

#define NATOMS 13
#define NP (NATOMS * NATOMS)   // 169

constexpr int N_ = 1024;   // rows
constexpr int H_ = 512;    // inner dim
constexpr int O_ = 512;    // output dim
constexpr int RB = 4;      // rows per W stream (quad)
constexpr int OSPLIT = 2;
constexpr int OC = O_ / OSPLIT;        // 256 cols per panel (1KB contiguous)
constexpr int HPH = 8;                 // h-segments = waves per block
constexpr int HSEG = H_ / HPH;         // 64 contiguous rows per wave
constexpr int MAXQUAD = 384;           // >= sum ceil(c_g/4) (<=383)
constexpr int NB = MAXQUAD * OSPLIT;   // 768 blocks (div by 8)
constexpr int RECS = 8;    // ints per quad record: rows[4], id, pad

// ws ints: [0] nquads; records at ws+16: [quad*RECS + {0..3}] rows, [+4] id
// ----------------------------------------------------------------- build quads
// R15's latency-optimized build (proven): 1024 threads, packed Hillis-Steele.
__global__ __launch_bounds__(1024)
void build_quads(const int* __restrict__ x,
                 const int* __restrict__ fact,
                 int* __restrict__ ws, int N) {
    __shared__ int s_id[N_];
    __shared__ int s_cnt[NP];
    __shared__ int s_pos[NP];
    __shared__ int s_scan[256];
    __shared__ int s_sorted[N_];
    const int tid = threadIdx.x;

    if (tid < NP) { s_cnt[tid] = 0; s_pos[tid] = 0; }
    __syncthreads();

    const int f0 = fact[2 * tid];
    const int id = x[f0 * 3 + 1] * NATOMS + x[f0 * 3 + 2];
    s_id[tid] = id;
    atomicAdd(&s_cnt[id], 1);
    __syncthreads();

    if (tid < 256) {
        const int c = (tid < NP) ? s_cnt[tid] : 0;
        s_scan[tid] = c | (((c + RB - 1) >> 2) << 16);
    }
    __syncthreads();
#pragma unroll
    for (int off = 1; off < 256; off <<= 1) {
        int nv = 0;
        if (tid < 256) {
            nv = s_scan[tid];
            if (tid >= off) nv += s_scan[tid - off];
        }
        __syncthreads();
        if (tid < 256) s_scan[tid] = nv;
        __syncthreads();
    }
    if (tid == 0) ws[0] = s_scan[NP - 1] >> 16;   // nquads

    const int st_me = id ? (s_scan[id - 1] & 0xffff) : 0;
    const int p = atomicAdd(&s_pos[id], 1);
    s_sorted[st_me + p] = tid;
    __syncthreads();

    if (tid < NP) {
        const int g  = tid;
        const int c  = s_cnt[g];
        const int st = g ? (s_scan[g - 1] & 0xffff) : 0;
        const int qs = g ? (s_scan[g - 1] >> 16) : 0;
        const int nq = (c + RB - 1) >> 2;
        for (int k = 0; k < nq; ++k) {
            int* rec = ws + 16 + (size_t)(qs + k) * RECS;
#pragma unroll
            for (int r = 0; r < RB; ++r) {
                const int idx = k * RB + r;
                rec[r] = (idx < c) ? s_sorted[st + idx] : -1;
            }
            rec[RB] = g;
        }
    }
}

// ------------------------------------------------------------------ quad GEMV
// R15 geometry with ONE change: wave sub streams the CONTIGUOUS row segment
// h in [64*sub, 64*sub+64) (sequential 128KB region, 1KB loads at 2KB
// stride) instead of the stride-8 comb. Same totals, same 8-way LDS reduce,
// direct stores, no atomics.
__global__ __launch_bounds__(512)
void quad_gemv(const int* __restrict__ ws,
               const float* __restrict__ inp,
               const float* __restrict__ params,
               const float* __restrict__ bias,
               const int* __restrict__ msg_to_p,
               const int* __restrict__ order_p,
               float* __restrict__ out, int N) {
    constexpr int q8 = NB / 8;
    const int b = blockIdx.x;
    const int Lg = (b & 7) * q8 + (b >> 3);
    const int quad = Lg >> 1;
    const int op   = Lg & 1;

    if (quad >= ws[0]) return;
    const int* rec = ws + 16 + (size_t)quad * RECS;
    const int id = rec[RB];

    const int msg_to = *msg_to_p;
    const int order  = *order_p;
    const int tid = threadIdx.x;
    const int sub = tid >> 6;        // 0..7: contiguous h-segment per wave
    const int l   = tid & 63;        // col-quad within 256-col panel
    const int o0  = op * OC;

    __shared__ float  fp_s[H_][RB];        // 8 KB, [h][r]
    __shared__ float4 red[HPH][RB][64];    // 32 KB, [sub][r][l]

    // stage fact_prod: 512 threads -> one h per thread per row, single pass
#pragma unroll
    for (int r = 0; r < RB; ++r) {
        const int row = rec[r];
        float p = 0.0f;
        if (row >= 0) {
            p = 1.0f;
            for (int i = 0; i < order; ++i)
                if (i != msg_to)
                    p *= inp[((size_t)i * N + row) * H_ + tid];
        }
        fp_s[tid][r] = p;
    }
    __syncthreads();

    // wave sub: sequential rows h = HSEG*sub + hh, hh in [0, 64)
    const float* __restrict__ wbase =
        params + (size_t)id * H_ * O_ + (size_t)(HSEG * sub) * O_ + o0 + 4 * l;

    float4 a0 = make_float4(0,0,0,0), a1 = a0, a2 = a0, a3 = a0;

#define FMA4(acc, s, wv) acc.x += (s) * wv.x; acc.y += (s) * wv.y;    \
                         acc.z += (s) * wv.z; acc.w += (s) * wv.w;
#pragma unroll 8
    for (int hh = 0; hh < HSEG; ++hh) {
        const float4 w = *(const float4*)(wbase + (size_t)hh * O_);
        const float4 f = *(const float4*)&fp_s[HSEG * sub + hh][0];
        FMA4(a0, f.x, w)
        FMA4(a1, f.y, w)
        FMA4(a2, f.z, w)
        FMA4(a3, f.w, w)
    }
#undef FMA4

    red[sub][0][l] = a0;
    red[sub][1][l] = a1;
    red[sub][2][l] = a2;
    red[sub][3][l] = a3;
    __syncthreads();

    if (tid < RB * 64) {
        const int r  = tid >> 6;
        const int l2 = tid & 63;
        const int row = rec[r];
        if (row >= 0) {
            float4 s = red[0][r][l2];
#pragma unroll
            for (int ss = 1; ss < HPH; ++ss) {
                const float4 p = red[ss][r][l2];
                s.x += p.x; s.y += p.y; s.z += p.z; s.w += p.w;
            }
            const float4 bv = *(const float4*)(bias + (size_t)id * O_ + o0 + 4 * l2);
            s.x += bv.x; s.y += bv.y; s.z += bv.z; s.w += bv.w;
            *(float4*)(out + (size_t)row * O_ + o0 + 4 * l2) = s;
        }
    }
}

// ---------------------------------------------------------------------- launch
extern "C" void kernel_launch(void* const* d_in, const int* in_sizes, int n_in,
                              void* d_out, int out_size, void* d_ws, size_t ws_size,
                              hipStream_t stream) {
    const int*   x      = (const int*)d_in[0];
    const int*   fact   = (const int*)d_in[1];
    const float* inp    = (const float*)d_in[2];
    const float* params = (const float*)d_in[3];
    const float* bias   = (const float*)d_in[4];
    const int*   msg_to = (const int*)d_in[5];
    const int*   order  = (const int*)d_in[6];
    float*       out    = (float*)d_out;

    const int N = in_sizes[1] / 2;   // 1024
    int* ws = (int*)d_ws;

    hipLaunchKernelGGL(build_quads, dim3(1), dim3(1024), 0, stream,
                       x, fact, ws, N);

    hipLaunchKernelGGL(quad_gemv, dim3(NB), dim3(512), 0, stream,
                       ws, inp, params, bias, msg_to, order, out, N);
}